// Round 1
// baseline (89.918 us; speedup 1.0000x reference)
//
#include <hip/hip_runtime.h>
#include <math.h>

#define N 8192
#define D 1024

// Kernel 1: per-row dot products. One wave (64 lanes) per row; 4 rows per 256-thr block.
__global__ __launch_bounds__(256) void dot_rows(const float* __restrict__ q,
                                                const float* __restrict__ k,
                                                float* __restrict__ raw) {
    const int wave = threadIdx.x >> 6;
    const int lane = threadIdx.x & 63;
    const int row  = blockIdx.x * 4 + wave;
    const float4* q4 = (const float4*)(q + (size_t)row * D);
    const float4* k4 = (const float4*)(k + (size_t)row * D);
    float s = 0.f;
    #pragma unroll
    for (int i = 0; i < 4; ++i) {             // D/4 = 256 float4s, 64 lanes -> 4 each
        float4 a = q4[lane + 64 * i];
        float4 b = k4[lane + 64 * i];
        s += a.x * b.x + a.y * b.y + a.z * b.z + a.w * b.w;
    }
    #pragma unroll
    for (int off = 32; off; off >>= 1) s += __shfl_down(s, off, 64);
    if (lane == 0) raw[row] = s;
}

// Kernel 2: softmax over 8192 scalars. Single block, 1024 threads, 8 values/thread.
__global__ __launch_bounds__(1024) void softmax_vec(const float* __restrict__ raw,
                                                    float* __restrict__ sm) {
    const int t    = threadIdx.x;
    const int lane = t & 63;
    const int wid  = t >> 6;                  // 16 waves
    __shared__ float red[16];

    float v[8];
    float m = -INFINITY;
    #pragma unroll
    for (int i = 0; i < 8; ++i) {
        v[i] = raw[t + 1024 * i];
        m = fmaxf(m, v[i]);
    }
    #pragma unroll
    for (int off = 32; off; off >>= 1) m = fmaxf(m, __shfl_down(m, off, 64));
    if (lane == 0) red[wid] = m;
    __syncthreads();
    if (wid == 0) {
        float mm = (lane < 16) ? red[lane] : -INFINITY;
        #pragma unroll
        for (int off = 8; off; off >>= 1) mm = fmaxf(mm, __shfl_down(mm, off, 64));
        if (lane == 0) red[0] = mm;
    }
    __syncthreads();
    m = red[0];
    __syncthreads();                           // red[] reused below

    float s = 0.f;
    #pragma unroll
    for (int i = 0; i < 8; ++i) {
        v[i] = __expf(v[i] - m);
        s += v[i];
    }
    #pragma unroll
    for (int off = 32; off; off >>= 1) s += __shfl_down(s, off, 64);
    if (lane == 0) red[wid] = s;
    __syncthreads();
    if (wid == 0) {
        float ss = (lane < 16) ? red[lane] : 0.f;
        #pragma unroll
        for (int off = 8; off; off >>= 1) ss += __shfl_down(ss, off, 64);
        if (lane == 0) red[0] = ss;
    }
    __syncthreads();
    const float inv = 1.0f / red[0];
    #pragma unroll
    for (int i = 0; i < 8; ++i) sm[t + 1024 * i] = v[i] * inv;
}

// Kernel 3: zero-fill the 256 MB output with float4 stores, planting sm[row] on the diagonal.
__global__ __launch_bounds__(256) void fill_diag(float* __restrict__ out,
                                                 const float* __restrict__ sm) {
    const size_t total4 = (size_t)N * N / 4;   // 16M float4s
    const size_t stride = (size_t)gridDim.x * blockDim.x;
    for (size_t i4 = (size_t)blockIdx.x * blockDim.x + threadIdx.x; i4 < total4; i4 += stride) {
        const size_t o  = i4 << 2;             // flat float index
        const int row   = (int)(o >> 13);      // / N
        float4 v = make_float4(0.f, 0.f, 0.f, 0.f);
        // diag of row r sits at col r; inside this float4 iff col4-base == r&~3
        if ((unsigned)((o >> 2) & (N / 4 - 1)) == (unsigned)(row >> 2)) {
            ((float*)&v)[row & 3] = sm[row];
        }
        ((float4*)out)[i4] = v;
    }
}

extern "C" void kernel_launch(void* const* d_in, const int* in_sizes, int n_in,
                              void* d_out, int out_size, void* d_ws, size_t ws_size,
                              hipStream_t stream) {
    const float* q = (const float*)d_in[0];
    const float* k = (const float*)d_in[1];
    float* out = (float*)d_out;
    float* raw = (float*)d_ws;                 // 8192 floats
    float* sm  = raw + N;                      // 8192 floats

    dot_rows<<<N / 4, 256, 0, stream>>>(q, k, raw);
    softmax_vec<<<1, 1024, 0, stream>>>(raw, sm);
    fill_diag<<<2048, 256, 0, stream>>>(out, sm);
}

// Round 2
// 72.223 us; speedup vs baseline: 1.2450x; 1.2450x over previous
//
#include <hip/hip_runtime.h>
#include <math.h>

#define N 8192
#define D 1024

// Kernel 1: per-row dot products. One wave (64 lanes) per row; 4 rows per 256-thr block.
__global__ __launch_bounds__(256) void dot_rows(const float* __restrict__ q,
                                                const float* __restrict__ k,
                                                float* __restrict__ raw) {
    const int wave = threadIdx.x >> 6;
    const int lane = threadIdx.x & 63;
    const int row  = blockIdx.x * 4 + wave;
    const float4* q4 = (const float4*)(q + (size_t)row * D);
    const float4* k4 = (const float4*)(k + (size_t)row * D);
    float s = 0.f;
    #pragma unroll
    for (int i = 0; i < 4; ++i) {             // D/4 = 256 float4s, 64 lanes -> 4 each
        float4 a = q4[lane + 64 * i];
        float4 b = k4[lane + 64 * i];
        s += a.x * b.x + a.y * b.y + a.z * b.z + a.w * b.w;
    }
    #pragma unroll
    for (int off = 32; off; off >>= 1) s += __shfl_down(s, off, 64);
    if (lane == 0) raw[row] = s;
}

// Kernel 2: softmax over 8192 scalars + scatter onto the (already-zeroed) diagonal.
// Single block, 1024 threads, 8 values/thread.
__global__ __launch_bounds__(1024) void softmax_scatter(const float* __restrict__ raw,
                                                        float* __restrict__ out) {
    const int t    = threadIdx.x;
    const int lane = t & 63;
    const int wid  = t >> 6;                  // 16 waves
    __shared__ float red[16];

    float v[8];
    float m = -INFINITY;
    #pragma unroll
    for (int i = 0; i < 8; ++i) {
        v[i] = raw[t + 1024 * i];
        m = fmaxf(m, v[i]);
    }
    #pragma unroll
    for (int off = 32; off; off >>= 1) m = fmaxf(m, __shfl_down(m, off, 64));
    if (lane == 0) red[wid] = m;
    __syncthreads();
    if (wid == 0) {
        float mm = (lane < 16) ? red[lane] : -INFINITY;
        #pragma unroll
        for (int off = 8; off; off >>= 1) mm = fmaxf(mm, __shfl_down(mm, off, 64));
        if (lane == 0) red[0] = mm;
    }
    __syncthreads();
    m = red[0];
    __syncthreads();                           // red[] reused below

    float s = 0.f;
    #pragma unroll
    for (int i = 0; i < 8; ++i) {
        v[i] = __expf(v[i] - m);
        s += v[i];
    }
    #pragma unroll
    for (int off = 32; off; off >>= 1) s += __shfl_down(s, off, 64);
    if (lane == 0) red[wid] = s;
    __syncthreads();
    if (wid == 0) {
        float ss = (lane < 16) ? red[lane] : 0.f;
        #pragma unroll
        for (int off = 8; off; off >>= 1) ss += __shfl_down(ss, off, 64);
        if (lane == 0) red[0] = ss;
    }
    __syncthreads();
    const float inv = 1.0f / red[0];
    #pragma unroll
    for (int i = 0; i < 8; ++i) {
        const int row = t + 1024 * i;
        out[(size_t)row * (N + 1)] = v[i] * inv;   // diagonal element (row,row)
    }
}

extern "C" void kernel_launch(void* const* d_in, const int* in_sizes, int n_in,
                              void* d_out, int out_size, void* d_ws, size_t ws_size,
                              hipStream_t stream) {
    const float* q = (const float*)d_in[0];
    const float* k = (const float*)d_in[1];
    float* out = (float*)d_out;
    float* raw = (float*)d_ws;                 // 8192 floats

    // Zero the full 256 MB output with the ROCm fill kernel (measured ~7 TB/s).
    hipMemsetAsync(out, 0, (size_t)N * N * sizeof(float), stream);
    dot_rows<<<N / 4, 256, 0, stream>>>(q, k, raw);
    softmax_scatter<<<1, 1024, 0, stream>>>(raw, out);
}

// Round 4
// 66.662 us; speedup vs baseline: 1.3489x; 1.0834x over previous
//
#include <hip/hip_runtime.h>
#include <math.h>

#define N 8192
#define D 1024

typedef float f32x4 __attribute__((ext_vector_type(4)));

// Fused kernel: odd blocks compute per-row dots (4 rows/block, 1 wave/row);
// even blocks zero-fill a contiguous 128 KiB slice of the output with
// non-temporal float4 stores. 4096 blocks total: 2048 fill + 2048 dot,
// parity-interleaved so reads and writes overlap on the HBM bus throughout.
__global__ __launch_bounds__(256) void fill_and_dot(const float* __restrict__ q,
                                                    const float* __restrict__ k,
                                                    float* __restrict__ raw,
                                                    float* __restrict__ out) {
    const int bid = blockIdx.x;
    if (bid & 1) {
        // ---- dot role: rows 4*(bid>>1) .. +3 ----
        const int wave = threadIdx.x >> 6;
        const int lane = threadIdx.x & 63;
        const int row  = (bid >> 1) * 4 + wave;
        const float4* q4 = (const float4*)(q + (size_t)row * D);
        const float4* k4 = (const float4*)(k + (size_t)row * D);
        float s = 0.f;
        #pragma unroll
        for (int i = 0; i < 4; ++i) {         // D/4 = 256 float4s, 64 lanes -> 4 each
            float4 a = q4[lane + 64 * i];
            float4 b = k4[lane + 64 * i];
            s += a.x * b.x + a.y * b.y + a.z * b.z + a.w * b.w;
        }
        #pragma unroll
        for (int off = 32; off; off >>= 1) s += __shfl_down(s, off, 64);
        if (lane == 0) raw[row] = s;
    } else {
        // ---- fill role: 32768 floats = 8192 float4s per block ----
        const int fb = bid >> 1;              // 0..2047
        f32x4* o4 = (f32x4*)out + (size_t)fb * 8192 + threadIdx.x;
        const f32x4 z = {0.f, 0.f, 0.f, 0.f};
        #pragma unroll
        for (int i = 0; i < 32; ++i)
            __builtin_nontemporal_store(z, o4 + i * 256);
    }
}

// Softmax over 8192 scalars + scatter onto the (already-zeroed) diagonal.
// Single block, 1024 threads, 8 values/thread.
__global__ __launch_bounds__(1024) void softmax_scatter(const float* __restrict__ raw,
                                                        float* __restrict__ out) {
    const int t    = threadIdx.x;
    const int lane = t & 63;
    const int wid  = t >> 6;                  // 16 waves
    __shared__ float red[16];

    float v[8];
    float m = -INFINITY;
    #pragma unroll
    for (int i = 0; i < 8; ++i) {
        v[i] = raw[t + 1024 * i];
        m = fmaxf(m, v[i]);
    }
    #pragma unroll
    for (int off = 32; off; off >>= 1) m = fmaxf(m, __shfl_down(m, off, 64));
    if (lane == 0) red[wid] = m;
    __syncthreads();
    if (wid == 0) {
        float mm = (lane < 16) ? red[lane] : -INFINITY;
        #pragma unroll
        for (int off = 8; off; off >>= 1) mm = fmaxf(mm, __shfl_down(mm, off, 64));
        if (lane == 0) red[0] = mm;
    }
    __syncthreads();
    m = red[0];
    __syncthreads();                           // red[] reused below

    float s = 0.f;
    #pragma unroll
    for (int i = 0; i < 8; ++i) {
        v[i] = __expf(v[i] - m);
        s += v[i];
    }
    #pragma unroll
    for (int off = 32; off; off >>= 1) s += __shfl_down(s, off, 64);
    if (lane == 0) red[wid] = s;
    __syncthreads();
    if (wid == 0) {
        float ss = (lane < 16) ? red[lane] : 0.f;
        #pragma unroll
        for (int off = 8; off; off >>= 1) ss += __shfl_down(ss, off, 64);
        if (lane == 0) red[0] = ss;
    }
    __syncthreads();
    const float inv = 1.0f / red[0];
    #pragma unroll
    for (int i = 0; i < 8; ++i) {
        const int row = t + 1024 * i;
        out[(size_t)row * (N + 1)] = v[i] * inv;   // diagonal element (row,row)
    }
}

extern "C" void kernel_launch(void* const* d_in, const int* in_sizes, int n_in,
                              void* d_out, int out_size, void* d_ws, size_t ws_size,
                              hipStream_t stream) {
    const float* q = (const float*)d_in[0];
    const float* k = (const float*)d_in[1];
    float* out = (float*)d_out;
    float* raw = (float*)d_ws;                 // 8192 floats

    fill_and_dot<<<4096, 256, 0, stream>>>(q, k, raw, out);
    softmax_scatter<<<1, 1024, 0, stream>>>(raw, out);
}

// Round 5
// 66.619 us; speedup vs baseline: 1.3497x; 1.0006x over previous
//
#include <hip/hip_runtime.h>
#include <math.h>

#define N 8192
#define D 1024

typedef float f32x4 __attribute__((ext_vector_type(4)));

// K1: per-row dot products. One wave (64 lanes) per row; 4 rows per 256-thr block.
__global__ __launch_bounds__(256) void dot_rows(const float* __restrict__ q,
                                                const float* __restrict__ k,
                                                float* __restrict__ raw) {
    const int wave = threadIdx.x >> 6;
    const int lane = threadIdx.x & 63;
    const int row  = blockIdx.x * 4 + wave;
    const float4* q4 = (const float4*)(q + (size_t)row * D);
    const float4* k4 = (const float4*)(k + (size_t)row * D);
    float s = 0.f;
    #pragma unroll
    for (int i = 0; i < 4; ++i) {             // D/4 = 256 float4s, 64 lanes -> 4 each
        float4 a = q4[lane + 64 * i];
        float4 b = k4[lane + 64 * i];
        s += a.x * b.x + a.y * b.y + a.z * b.z + a.w * b.w;
    }
    #pragma unroll
    for (int off = 32; off; off >>= 1) s += __shfl_down(s, off, 64);
    if (lane == 0) raw[row] = s;
}

// K2: block 0 = softmax over raw[8192] + scatter diag values.
//     blocks 1..2048 = zero-fill 4 rows each (32768 floats), skipping the one
//     diagonal word per row (block 0 owns those addresses). Disjoint writes,
//     no ordering needed; softmax hides under the 256 MB fill.
__global__ __launch_bounds__(256) void fill_and_softmax(const float* __restrict__ raw,
                                                        float* __restrict__ out) {
    const int bid = blockIdx.x;
    const int t   = threadIdx.x;

    if (bid == 0) {
        // ---- softmax + diagonal scatter (256 threads, 32 rows each) ----
        const int lane = t & 63;
        const int wid  = t >> 6;              // 4 waves
        __shared__ float red[4];

        // pass 1: max
        float m = -INFINITY;
        #pragma unroll
        for (int i = 0; i < 32; ++i) m = fmaxf(m, raw[t + 256 * i]);
        #pragma unroll
        for (int off = 32; off; off >>= 1) m = fmaxf(m, __shfl_down(m, off, 64));
        if (lane == 0) red[wid] = m;
        __syncthreads();
        m = fmaxf(fmaxf(red[0], red[1]), fmaxf(red[2], red[3]));
        __syncthreads();

        // pass 2: sum of exp
        float s = 0.f;
        #pragma unroll
        for (int i = 0; i < 32; ++i) s += __expf(raw[t + 256 * i] - m);
        #pragma unroll
        for (int off = 32; off; off >>= 1) s += __shfl_down(s, off, 64);
        if (lane == 0) red[wid] = s;
        __syncthreads();
        const float inv = 1.0f / (red[0] + red[1] + red[2] + red[3]);

        // pass 3: write diagonal entries
        #pragma unroll
        for (int i = 0; i < 32; ++i) {
            const int r = t + 256 * i;
            out[(size_t)r * (N + 1)] = __expf(raw[r] - m) * inv;
        }
    } else {
        // ---- fill role: rows 4*fb .. 4*fb+3, 8192 float4s per block ----
        const int fb = bid - 1;               // 0..2047
        f32x4* o4 = (f32x4*)out + (size_t)fb * 8192;
        const f32x4 z = {0.f, 0.f, 0.f, 0.f};
        #pragma unroll
        for (int i = 0; i < 32; ++i) {
            const int g = t + 256 * i;        // within-slice float4 index
            if ((g & 2047) == fb) {
                // this float4 contains the diagonal of row 4*fb + (g>>11);
                // write the 3 non-diagonal words only
                const int j = g >> 11;        // word to skip
                float* w = (float*)(o4 + g);
                #pragma unroll
                for (int c = 0; c < 4; ++c)
                    if (c != j) __builtin_nontemporal_store(0.f, w + c);
            } else {
                __builtin_nontemporal_store(z, o4 + g);
            }
        }
    }
}

extern "C" void kernel_launch(void* const* d_in, const int* in_sizes, int n_in,
                              void* d_out, int out_size, void* d_ws, size_t ws_size,
                              hipStream_t stream) {
    const float* q = (const float*)d_in[0];
    const float* k = (const float*)d_in[1];
    float* out = (float*)d_out;
    float* raw = (float*)d_ws;                 // 8192 floats

    dot_rows<<<N / 4, 256, 0, stream>>>(q, k, raw);
    fill_and_softmax<<<N / 4 + 1, 256, 0, stream>>>(raw, out);
}